// Round 1
// baseline (4838.272 us; speedup 1.0000x reference)
//
#include <hip/hip_runtime.h>
#include <hip/hip_bf16.h>

typedef unsigned short u16;
typedef unsigned int u32;
typedef __attribute__((ext_vector_type(4))) float f32x4;
typedef __attribute__((ext_vector_type(8))) short s16x8;

#define OREC 8388608
#define OH 16777216
#define OLOSS 17301504

__device__ __forceinline__ float bf2f(u16 u) {
    union { u32 i; float f; } v; v.i = ((u32)u) << 16; return v.f;
}
__device__ __forceinline__ u16 f2bf(float f) {
    union { float f; u32 i; } v; v.f = f;
    u32 i = v.i;
    u32 r = i + 0x7FFFu + ((i >> 16) & 1u);
    return (u16)(r >> 16);
}
__device__ __forceinline__ float ldin(const void* p, int i, int bf) {
    return bf ? bf2f(((const u16*)p)[i]) : ((const float*)p)[i];
}
__device__ __forceinline__ void stout(void* p, int i, float v, int bf) {
    if (bf) ((u16*)p)[i] = f2bf(v); else ((float*)p)[i] = v;
}

#define ZACC(A) do { \
    _Pragma("unroll") for (int zi = 0; zi < 2; ++zi) \
    _Pragma("unroll") for (int zj = 0; zj < 2; ++zj) \
    _Pragma("unroll") for (int zq = 0; zq < 4; ++zq) A[zi][zj][zq] = 0.f; \
} while (0)

// ---- GEMM core: C[64x64] tile, 256 threads (4 waves 2x2), mfma 16x16x32 bf16 ----
__device__ __forceinline__ void stage_tile(const u16* __restrict__ src, int ld, int row0, int k0,
                                           u16* lds) {
    int t = threadIdx.x;
    int row = t >> 2, seg = t & 3;
    const u16* g = src + (size_t)(row0 + row) * ld + k0 + (seg << 3);
    uint4 v = *(const uint4*)g;
    *(uint4*)&lds[(row << 5) + ((seg ^ (row & 3)) << 3)] = v;
}

__device__ __forceinline__ void gemm_loop(const u16* __restrict__ A, int lda,
                                          const u16* __restrict__ W, int ldw,
                                          int K, int m0, int n0,
                                          u16* lA, u16* lB, f32x4 acc[2][2]) {
    int lane = threadIdx.x & 63;
    int wid = threadIdx.x >> 6;
    int wr = wid >> 1, wc = wid & 1;
    int lrow = lane & 15, lseg = lane >> 4;
    int sw = (lseg ^ (lrow & 3)) << 3;  // (row&3)==(lrow&3) since frag bases are multiples of 16
    for (int k0 = 0; k0 < K; k0 += 32) {
        __syncthreads();
        stage_tile(A, lda, m0, k0, lA);
        stage_tile(W, ldw, n0, k0, lB);
        __syncthreads();
        s16x8 af[2], bg[2];
#pragma unroll
        for (int i = 0; i < 2; i++) {
            int r = (wr << 5) + (i << 4) + lrow;
            af[i] = *(const s16x8*)&lA[(r << 5) + sw];
            int c = (wc << 5) + (i << 4) + lrow;
            bg[i] = *(const s16x8*)&lB[(c << 5) + sw];
        }
#pragma unroll
        for (int i = 0; i < 2; i++)
#pragma unroll
            for (int j = 0; j < 2; j++)
                acc[i][j] = __builtin_amdgcn_mfma_f32_16x16x32_bf16(af[i], bg[j], acc[i][j], 0, 0, 0);
    }
}

// Epilogue index helpers: row = m0+wr*32+i*16+(lane>>4)*4+q, col = n0+wc*32+j*16+(lane&15)

// ---- prologue kernels ----
__global__ void k_zero(int* flag, float* lossN, float* lossD) {
    if (threadIdx.x == 0) *flag = 0;
    if (threadIdx.x < 64) { lossN[threadIdx.x] = 0.f; lossD[threadIdx.x] = 0.f; }
}

__global__ void k_detect(const u32* __restrict__ w, int* flag) {
    int gid = blockIdx.x * 256 + threadIdx.x;
    int found = 0;
    for (int i = gid; i < (1 << 20); i += 65536) {
        if ((w[i] & 0xFFFFu) == 0x3F80u) found = 1;
    }
    if (found) atomicOr(flag, 1);
}

__global__ void k_cvt_bf(const void* __restrict__ src, u16* __restrict__ dst, int n,
                         const int* __restrict__ flagp) {
    int bf = *flagp;
    for (int i = blockIdx.x * 256 + threadIdx.x; i < n; i += gridDim.x * 256)
        dst[i] = bf ? ((const u16*)src)[i] : f2bf(((const float*)src)[i]);
}

__global__ void k_cvt_f32(const void* __restrict__ src, float* __restrict__ dst, int n,
                          const int* __restrict__ flagp) {
    int bf = *flagp;
    for (int i = blockIdx.x * 256 + threadIdx.x; i < n; i += gridDim.x * 256)
        dst[i] = ldin(src, i, bf);
}

__global__ void k_fixup(u16* __restrict__ WfrB, float* __restrict__ wdxd,
                        const void* __restrict__ Wdx, const int* __restrict__ flagp) {
    int f = threadIdx.x;  // 256
    int bf = *flagp;
    WfrB[f * 256 + f] = 0;            // zero the FeatureRegression diagonal
    wdxd[f] = ldin(Wdx, f * 257, bf); // Wdx[f][f]
}

// ---- per-step kernels ----
__global__ void k_prestep(const void* __restrict__ deltas, const void* __restrict__ mask,
                          int t, const int* __restrict__ flagp,
                          const float* __restrict__ wdxd, const float* __restrict__ bdx,
                          u16* __restrict__ dbf, u16* __restrict__ A2, u16* __restrict__ A3) {
    int bf = *flagp;
    int idx = (blockIdx.x << 8) + threadIdx.x;  // [0, 131072)
    int b = idx >> 8, f = idx & 255;
    int gidx = (b << 14) + (t << 8) + f;
    float d = ldin(deltas, gidx, bf);
    float m = ldin(mask, gidx, bf);
    dbf[idx] = f2bf(d);
    float gx = expf(-fmaxf(d * wdxd[f] + bdx[f], 0.f));
    int a2o = (b << 9) + f;
    A2[a2o] = f2bf(gx);
    u16 mb = f2bf(m);
    A2[a2o + 256] = mb;
    A3[a2o + 256] = mb;
}

__global__ __launch_bounds__(256) void k_decay(const u16* __restrict__ dbf,
                                               const u16* __restrict__ WdhB,
                                               const float* __restrict__ bdh,
                                               float* __restrict__ h, u16* __restrict__ hbf) {
    __shared__ u16 lA[2048], lB[2048];
    int m0 = blockIdx.x << 6, n0 = blockIdx.y << 6;
    f32x4 acc[2][2]; ZACC(acc);
    gemm_loop(dbf, 256, WdhB, 256, 256, m0, n0, lA, lB, acc);
    int lane = threadIdx.x & 63, wid = threadIdx.x >> 6;
    int wr = wid >> 1, wc = wid & 1;
    int rq = (lane >> 4) << 2, cc = lane & 15;
#pragma unroll
    for (int i = 0; i < 2; i++)
#pragma unroll
        for (int j = 0; j < 2; j++)
#pragma unroll
            for (int q = 0; q < 4; q++) {
                int gr = m0 + (wr << 5) + (i << 4) + rq + q;
                int gc = n0 + (wc << 5) + (j << 4) + cc;
                float g = expf(-fmaxf(acc[i][j][q] + bdh[gc], 0.f));
                int idx = (gr << 10) + gc;
                float nh = h[idx] * g;
                h[idx] = nh;
                hbf[idx] = f2bf(nh);
            }
}

__global__ __launch_bounds__(256) void k_hist(const u16* __restrict__ hbf,
                                              const u16* __restrict__ WhB,
                                              const float* __restrict__ bh,
                                              const void* __restrict__ x, const void* __restrict__ mask,
                                              int t, const int* __restrict__ flagp,
                                              float* __restrict__ xh, u16* __restrict__ xrbf) {
    __shared__ u16 lA[2048], lB[2048];
    int m0 = blockIdx.x << 6, n0 = blockIdx.y << 6;
    f32x4 acc[2][2]; ZACC(acc);
    gemm_loop(hbf, 1024, WhB, 1024, 1024, m0, n0, lA, lB, acc);
    int bf = *flagp;
    int lane = threadIdx.x & 63, wid = threadIdx.x >> 6;
    int wr = wid >> 1, wc = wid & 1;
    int rq = (lane >> 4) << 2, cc = lane & 15;
#pragma unroll
    for (int i = 0; i < 2; i++)
#pragma unroll
        for (int j = 0; j < 2; j++)
#pragma unroll
            for (int q = 0; q < 4; q++) {
                int gr = m0 + (wr << 5) + (i << 4) + rq + q;
                int gc = n0 + (wc << 5) + (j << 4) + cc;
                float v = acc[i][j][q] + bh[gc];
                int gidx = (gr << 14) + (t << 8) + gc;
                float mv = ldin(mask, gidx, bf);
                float xv = ldin(x, gidx, bf);
                xh[(gr << 8) + gc] = v;
                xrbf[(gr << 8) + gc] = f2bf(mv * xv + (1.f - mv) * v);
            }
}

__global__ __launch_bounds__(256) void k_comb(const u16* __restrict__ xrbf,
                                              const u16* __restrict__ WfrB, const float* __restrict__ bfr,
                                              const u16* __restrict__ A2,
                                              const u16* __restrict__ WwcB, const float* __restrict__ bwc,
                                              const float* __restrict__ xh,
                                              const void* __restrict__ x, const void* __restrict__ mask,
                                              int t, const int* __restrict__ flagp,
                                              void* __restrict__ out, u16* __restrict__ A3,
                                              float* __restrict__ lossN, float* __restrict__ lossD) {
    __shared__ u16 lA[2048], lB[2048];
    __shared__ float redN[4], redD[4];
    int m0 = blockIdx.x << 6, n0 = blockIdx.y << 6;
    f32x4 acc1[2][2], acc2[2][2];
    ZACC(acc1); ZACC(acc2);
    gemm_loop(xrbf, 256, WfrB, 256, 256, m0, n0, lA, lB, acc1);
    gemm_loop(A2, 512, WwcB, 512, 512, m0, n0, lA, lB, acc2);
    int bf = *flagp;
    int lane = threadIdx.x & 63, wid = threadIdx.x >> 6;
    int wr = wid >> 1, wc = wid & 1;
    int rq = (lane >> 4) << 2, cc = lane & 15;
    float ln = 0.f, ld = 0.f;
#pragma unroll
    for (int i = 0; i < 2; i++)
#pragma unroll
        for (int j = 0; j < 2; j++)
#pragma unroll
            for (int q = 0; q < 4; q++) {
                int gr = m0 + (wr << 5) + (i << 4) + rq + q;
                int gc = n0 + (wc << 5) + (j << 4) + cc;
                float xu = acc1[i][j][q] + bfr[gc];
                float beta = acc2[i][j][q] + bwc[gc];
                float xhv = xh[(gr << 8) + gc];
                float xc = beta * xu + (1.f - beta) * xhv;
                int gidx = (gr << 14) + (t << 8) + gc;
                float mv = ldin(mask, gidx, bf);
                float xv = ldin(x, gidx, bf);
                stout(out, OREC + gidx, xc, bf);       // reconstruction
                float xi = mv * xv + (1.f - mv) * xc;
                stout(out, gidx, xi, bf);              // x_imp
                A3[(gr << 9) + gc] = f2bf(xi);         // rnn_in first half
                ln += fabsf(xc - xv) * mv;
                ld += mv;
            }
    for (int o = 32; o > 0; o >>= 1) { ln += __shfl_down(ln, o); ld += __shfl_down(ld, o); }
    if (lane == 0) { redN[wid] = ln; redD[wid] = ld; }
    __syncthreads();
    if (threadIdx.x == 0) {
        atomicAdd(&lossN[t], redN[0] + redN[1] + redN[2] + redN[3]);
        atomicAdd(&lossD[t], redD[0] + redD[1] + redD[2] + redD[3]);
    }
}

__global__ __launch_bounds__(256) void k_gates(const u16* __restrict__ A3,
                                               const u16* __restrict__ WihB, const float* __restrict__ bih,
                                               const u16* __restrict__ hbf,
                                               const u16* __restrict__ WhhB, const float* __restrict__ bhh,
                                               float* __restrict__ gi, float* __restrict__ gh) {
    __shared__ u16 lA[2048], lB[2048];
    int m0 = blockIdx.x << 6, n0 = blockIdx.y << 6;
    f32x4 acc[2][2]; ZACC(acc);
    const float* bias;
    float* out;
    if (blockIdx.z == 0) {
        gemm_loop(A3, 512, WihB, 512, 512, m0, n0, lA, lB, acc);
        bias = bih; out = gi;
    } else {
        gemm_loop(hbf, 1024, WhhB, 1024, 1024, m0, n0, lA, lB, acc);
        bias = bhh; out = gh;
    }
    int lane = threadIdx.x & 63, wid = threadIdx.x >> 6;
    int wr = wid >> 1, wc = wid & 1;
    int rq = (lane >> 4) << 2, cc = lane & 15;
#pragma unroll
    for (int i = 0; i < 2; i++)
#pragma unroll
        for (int j = 0; j < 2; j++)
#pragma unroll
            for (int q = 0; q < 4; q++) {
                int gr = m0 + (wr << 5) + (i << 4) + rq + q;
                int gc = n0 + (wc << 5) + (j << 4) + cc;
                out[gr * 3072 + gc] = acc[i][j][q] + bias[gc];
            }
}

__global__ void k_gru(const float* __restrict__ gi, const float* __restrict__ gh,
                      float* __restrict__ h) {
    int idx = (blockIdx.x << 8) + threadIdx.x;  // [0, 524288)
    int b = idx >> 10, j = idx & 1023;
    int o = b * 3072;
    float ir = gi[o + j], iz = gi[o + 1024 + j], inn = gi[o + 2048 + j];
    float hr = gh[o + j], hz = gh[o + 1024 + j], hn = gh[o + 2048 + j];
    float r = 1.f / (1.f + expf(-(ir + hr)));
    float z = 1.f / (1.f + expf(-(iz + hz)));
    float n = tanhf(inn + r * hn);
    h[idx] = (1.f - z) * n + z * h[idx];
}

// ---- epilogue kernels ----
__global__ void k_hout(const float* __restrict__ h, void* __restrict__ out,
                       const int* __restrict__ flagp) {
    int bf = *flagp;
    int i = (blockIdx.x << 8) + threadIdx.x;  // 524288
    stout(out, OH + i, h[i], bf);
}

__global__ void k_loss(const float* __restrict__ lossN, const float* __restrict__ lossD,
                       void* __restrict__ out, const int* __restrict__ flagp) {
    int t = threadIdx.x;  // 64
    float v = lossN[t] / (lossD[t] + 1e-12f);
    for (int o = 32; o > 0; o >>= 1) v += __shfl_down(v, o);
    if (t == 0) {
        int bf = *flagp;
        stout(out, OLOSS, v, bf);
        stout(out, OLOSS + 1, 0.f, bf);
    }
}

extern "C" void kernel_launch(void* const* d_in, const int* in_sizes, int n_in,
                              void* d_out, int out_size, void* d_ws, size_t ws_size,
                              hipStream_t stream) {
    (void)in_sizes; (void)n_in; (void)out_size; (void)ws_size;
    const void* x = d_in[0];
    const void* mask = d_in[1];
    const void* deltas = d_in[2];
    const void* h0 = d_in[3];
    const void* Wdh = d_in[4];  const void* bdh = d_in[5];
    const void* Wdx = d_in[6];  const void* bdx = d_in[7];
    const void* Wh = d_in[8];   const void* bh = d_in[9];
    const void* Wfr = d_in[10]; const void* bfr = d_in[11];
    const void* Wwc = d_in[12]; const void* bwc = d_in[13];
    const void* Wih = d_in[14]; const void* bih = d_in[15];
    const void* Whh = d_in[16]; const void* bhh = d_in[17];

    char* cur = (char*)d_ws;
    auto carve = [&](size_t bytes) -> char* {
        char* p = cur; cur += (bytes + 255) & ~(size_t)255; return p;
    };
    int* flag = (int*)carve(sizeof(int));
    float* lossN = (float*)carve(64 * 4);
    float* lossD = (float*)carve(64 * 4);
    float* wdxd = (float*)carve(256 * 4);
    float* bdhF = (float*)carve(1024 * 4);
    float* bdxF = (float*)carve(256 * 4);
    float* bhF = (float*)carve(256 * 4);
    float* bfrF = (float*)carve(256 * 4);
    float* bwcF = (float*)carve(256 * 4);
    float* bihF = (float*)carve(3072 * 4);
    float* bhhF = (float*)carve(3072 * 4);
    u16* WdhB = (u16*)carve(262144 * 2);
    u16* WhB = (u16*)carve(262144 * 2);
    u16* WfrB = (u16*)carve(65536 * 2);
    u16* WwcB = (u16*)carve(131072 * 2);
    u16* WihB = (u16*)carve(1572864 * 2);
    u16* WhhB = (u16*)carve(3145728 * 2);
    float* h = (float*)carve(524288 * 4);
    u16* hbf = (u16*)carve(524288 * 2);
    u16* dbf = (u16*)carve(131072 * 2);
    u16* A2 = (u16*)carve(262144 * 2);
    u16* A3 = (u16*)carve(262144 * 2);
    float* xh = (float*)carve(131072 * 4);
    u16* xrbf = (u16*)carve(131072 * 2);
    float* gi = (float*)carve(1572864 * 4);
    float* gh = (float*)carve(1572864 * 4);

    // prologue: dtype detect + weight prep (runs every call; deterministic)
    k_zero<<<1, 64, 0, stream>>>(flag, lossN, lossD);
    k_detect<<<256, 256, 0, stream>>>((const u32*)mask, flag);
    k_cvt_bf<<<1024, 256, 0, stream>>>(Wdh, WdhB, 262144, flag);
    k_cvt_bf<<<1024, 256, 0, stream>>>(Wh, WhB, 262144, flag);
    k_cvt_bf<<<256, 256, 0, stream>>>(Wfr, WfrB, 65536, flag);
    k_cvt_bf<<<512, 256, 0, stream>>>(Wwc, WwcB, 131072, flag);
    k_cvt_bf<<<2048, 256, 0, stream>>>(Wih, WihB, 1572864, flag);
    k_cvt_bf<<<2048, 256, 0, stream>>>(Whh, WhhB, 3145728, flag);
    k_cvt_f32<<<4, 256, 0, stream>>>(bdh, bdhF, 1024, flag);
    k_cvt_f32<<<1, 256, 0, stream>>>(bdx, bdxF, 256, flag);
    k_cvt_f32<<<1, 256, 0, stream>>>(bh, bhF, 256, flag);
    k_cvt_f32<<<1, 256, 0, stream>>>(bfr, bfrF, 256, flag);
    k_cvt_f32<<<1, 256, 0, stream>>>(bwc, bwcF, 256, flag);
    k_cvt_f32<<<12, 256, 0, stream>>>(bih, bihF, 3072, flag);
    k_cvt_f32<<<12, 256, 0, stream>>>(bhh, bhhF, 3072, flag);
    k_cvt_f32<<<2048, 256, 0, stream>>>(h0, h, 524288, flag);
    k_fixup<<<1, 256, 0, stream>>>(WfrB, wdxd, Wdx, flag);

    for (int t = 0; t < 64; ++t) {
        k_prestep<<<512, 256, 0, stream>>>(deltas, mask, t, flag, wdxd, bdxF, dbf, A2, A3);
        k_decay<<<dim3(8, 16), 256, 0, stream>>>(dbf, WdhB, bdhF, h, hbf);
        k_hist<<<dim3(8, 4), 256, 0, stream>>>(hbf, WhB, bhF, x, mask, t, flag, xh, xrbf);
        k_comb<<<dim3(8, 4), 256, 0, stream>>>(xrbf, WfrB, bfrF, A2, WwcB, bwcF, xh, x, mask,
                                               t, flag, d_out, A3, lossN, lossD);
        k_gates<<<dim3(8, 48, 2), 256, 0, stream>>>(A3, WihB, bihF, hbf, WhhB, bhhF, gi, gh);
        k_gru<<<2048, 256, 0, stream>>>(gi, gh, h);
    }
    k_hout<<<2048, 256, 0, stream>>>(h, d_out, flag);
    k_loss<<<1, 64, 0, stream>>>(lossN, lossD, d_out, flag);
}